// Round 1
// baseline (217.628 us; speedup 1.0000x reference)
//
#include <hip/hip_runtime.h>
#include <cstdint>

#define DEV __device__ __forceinline__

typedef __bf16  bf16x8 __attribute__((ext_vector_type(8)));
typedef short   s16x8  __attribute__((ext_vector_type(8)));
typedef float   f32x4  __attribute__((ext_vector_type(4)));

// fp32 -> bf16 round-to-nearest-even
DEV unsigned short f2bf(float f){
  union { float f; unsigned u; } v; v.f = f;
  unsigned r = v.u + 0x7fffu + ((v.u >> 16) & 1u);
  return (unsigned short)(r >> 16);
}

// async global->LDS, 16B per lane; LDS dest must be uniform_base + lane*16
DEV void gl2lds16(const void* g, void* l){
  __builtin_amdgcn_global_load_lds((__attribute__((address_space(1))) void*)(void*)(g),
                                   (__attribute__((address_space(3))) void*)(l), 16, 0, 0);
}

DEV f32x4 mfma16(bf16x8 a, bf16x8 b, f32x4 c){
  return __builtin_amdgcn_mfma_f32_16x16x32_bf16(a, b, c, 0, 0, 0);
}

// ---------------------------------------------------------------- prep
__global__ __launch_bounds__(256) void cast_x_kernel(const float* __restrict__ in,
                                                     short* __restrict__ out){
  int i = blockIdx.x * 256 + threadIdx.x;          // 393216 threads, 8 elems each
  const float4* in4 = (const float4*)in;
  float4 f0 = in4[i*2], f1 = in4[i*2+1];
  s16x8 o;
  o[0]=(short)f2bf(f0.x); o[1]=(short)f2bf(f0.y); o[2]=(short)f2bf(f0.z); o[3]=(short)f2bf(f0.w);
  o[4]=(short)f2bf(f1.x); o[5]=(short)f2bf(f1.y); o[6]=(short)f2bf(f1.z); o[7]=(short)f2bf(f1.w);
  *(s16x8*)(out + i*8) = o;
}

// out[C][R] (bf16) = in[R][C] (fp32)
__global__ __launch_bounds__(256) void transpose_cast_kernel(const float* __restrict__ in,
                                                             short* __restrict__ out,
                                                             int R, int C){
  __shared__ float t[32][33];
  int tx = threadIdx.x & 31, ty = threadIdx.x >> 5;
  int c0 = blockIdx.x * 32, r0 = blockIdx.y * 32;
  for (int i = 0; i < 4; i++)
    t[ty + i*8][tx] = in[(r0 + ty + i*8)*C + c0 + tx];
  __syncthreads();
  for (int i = 0; i < 4; i++)
    out[(c0 + ty + i*8)*R + r0 + tx] = (short)f2bf(t[tx][ty + i*8]);
}

// ---------------------------------------------------------------- QKV GEMM
// C[m,j] = sum_k xb[m,k]*wqT[j,k];  M=4096 (b*1024+n), Ncols=2304, K=768
// epilogue scatters: q(b,h,n,d), k(b,h,n,d), v TRANSPOSED (b,h,d,n)
__global__ __launch_bounds__(256) void qkv_gemm_kernel(const short* __restrict__ xb,
                                                       const short* __restrict__ wqT,
                                                       short* __restrict__ qb,
                                                       short* __restrict__ kb,
                                                       short* __restrict__ vtb){
  __shared__ __align__(16) short As[128*32];
  __shared__ __align__(16) short Bs[128*32];
  const int tid = threadIdx.x, lane = tid & 63, wv = tid >> 6;
  const int quad = lane >> 4, mi = lane & 15;
  const int m0 = blockIdx.x * 128, n0 = blockIdx.y * 128;
  const int wrow = wv >> 1, wcol = wv & 1;
  f32x4 acc[4][4] = {};
  for (int k0 = 0; k0 < 768; k0 += 32){
    __syncthreads();
    for (int i = 0; i < 2; i++){
      int rbase = 32*wv + 16*i;
      int row = rbase + (lane >> 2);
      gl2lds16(xb  + (m0+row)*768 + k0 + (lane&3)*8, As + rbase*32 + lane*8);
      gl2lds16(wqT + (n0+row)*768 + k0 + (lane&3)*8, Bs + rbase*32 + lane*8);
    }
    __syncthreads();
    bf16x8 a[4], b[4];
    for (int mt = 0; mt < 4; mt++) a[mt] = *(const bf16x8*)(As + (wrow*64 + mt*16 + mi)*32 + quad*8);
    for (int nt = 0; nt < 4; nt++) b[nt] = *(const bf16x8*)(Bs + (wcol*64 + nt*16 + mi)*32 + quad*8);
    for (int mt = 0; mt < 4; mt++)
      for (int nt = 0; nt < 4; nt++)
        acc[mt][nt] = mfma16(a[mt], b[nt], acc[mt][nt]);
  }
  for (int nt = 0; nt < 4; nt++){
    int j = n0 + wcol*64 + nt*16 + mi;            // output col 0..2303
    int which = j / 768, rem = j % 768;
    int head = rem >> 6, d = rem & 63;
    for (int mt = 0; mt < 4; mt++)
      for (int r = 0; r < 4; r++){
        int m = m0 + wrow*64 + mt*16 + quad*4 + r;
        int bb = m >> 10, n = m & 1023;
        int bh = bb*12 + head;
        short hv = (short)f2bf(acc[mt][nt][r]);
        if (which == 0)      qb[(bh*1024 + n)*64 + d] = hv;   // unscaled (rel uses raw q)
        else if (which == 1) kb[(bh*1024 + n)*64 + d] = hv;
        else                 vtb[(bh*64 + d)*1024 + n] = hv;  // transposed
      }
  }
}

// ---------------------------------------------------------------- rel bias
// relH[bh,h,w,kh] = sum_d q[bh,h*32+w,d] * rel_pos_h[h-kh+31,d]
// relW[bh,h,w,kw] = sum_d q[bh,h*32+w,d] * rel_pos_w[w-kw+31,d]
// 1-wave blocks: 3072 relH blocks (bh,h,half) + 3072 relW blocks (w, rowtile)
__global__ __launch_bounds__(64) void rel_kernel(const short* __restrict__ qb,
                                                 const float* __restrict__ rph,
                                                 const float* __restrict__ rpw,
                                                 float* __restrict__ relH,
                                                 float* __restrict__ relW){
  int bid = blockIdx.x, lane = threadIdx.x, quad = lane >> 4, mi = lane & 15;
  f32x4 acc[2] = {};
  if (bid < 3072){
    int bh = bid >> 6, rest = bid & 63, h = rest >> 1, half = rest & 1;
    const short* qr = qb + (bh*1024 + h*32 + half*16 + mi)*64;
    bf16x8 a0 = *(const bf16x8*)(qr + quad*8);
    bf16x8 a1 = *(const bf16x8*)(qr + 32 + quad*8);
    for (int nt = 0; nt < 2; nt++){
      int kh = nt*16 + mi;
      const float* rr = rph + (h - kh + 31)*64;
      bf16x8 bb[2];
      for (int kk = 0; kk < 2; kk++){
        const float* p = rr + kk*32 + quad*8;
        s16x8 t;
        for (int e = 0; e < 8; e++) t[e] = (short)f2bf(p[e]);
        bb[kk] = __builtin_bit_cast(bf16x8, t);
      }
      acc[nt] = mfma16(a0, bb[0], acc[nt]);
      acc[nt] = mfma16(a1, bb[1], acc[nt]);
    }
    for (int nt = 0; nt < 2; nt++)
      for (int r = 0; r < 4; r++){
        int w = half*16 + quad*4 + r;
        relH[((bh*32 + h)*32 + w)*32 + nt*16 + mi] = acc[nt][r];
      }
  } else {
    int bid2 = bid - 3072, w = bid2 / 96, rt = bid2 % 96;
    int rg = rt*16 + mi, bh = rg >> 5, h = rg & 31;
    const short* qr = qb + (bh*1024 + h*32 + w)*64;
    bf16x8 a0 = *(const bf16x8*)(qr + quad*8);
    bf16x8 a1 = *(const bf16x8*)(qr + 32 + quad*8);
    for (int nt = 0; nt < 2; nt++){
      int kw = nt*16 + mi;
      const float* rr = rpw + (w - kw + 31)*64;
      bf16x8 bb[2];
      for (int kk = 0; kk < 2; kk++){
        const float* p = rr + kk*32 + quad*8;
        s16x8 t;
        for (int e = 0; e < 8; e++) t[e] = (short)f2bf(p[e]);
        bb[kk] = __builtin_bit_cast(bf16x8, t);
      }
      acc[nt] = mfma16(a0, bb[0], acc[nt]);
      acc[nt] = mfma16(a1, bb[1], acc[nt]);
    }
    for (int nt = 0; nt < 2; nt++)
      for (int r = 0; r < 4; r++){
        int rowg = rt*16 + quad*4 + r;                    // = bh*32+h of the output row
        relW[(rowg*32 + w)*32 + nt*16 + mi] = acc[nt][r];
      }
  }
}

// ---------------------------------------------------------------- flash attention
// grid (16 q-tiles, 48 bh); 64x64 tiles; online softmax; ao[b,n,head*64+d] bf16
__global__ __launch_bounds__(256) void flash_kernel(const short* __restrict__ qb,
                                                    const short* __restrict__ kb,
                                                    const short* __restrict__ vtb,
                                                    const float* __restrict__ relH,
                                                    const float* __restrict__ relW,
                                                    short* __restrict__ ao){
  __shared__ __align__(16) short Qt[64*64];
  __shared__ __align__(16) short Kt[64*64];
  __shared__ __align__(16) short Vt[64*64];   // [d][key]
  __shared__ __align__(16) short Pt[64*64];   // [qrow][key]
  __shared__ __align__(16) float rH[64*32];
  __shared__ __align__(16) float rW[64*32];
  const int tid = threadIdx.x, lane = tid & 63, wv = tid >> 6;
  const int quad = lane >> 4, mi = lane & 15;
  const int bh = blockIdx.y, n0 = blockIdx.x * 64;

  {
    const short* qg  = qb   + (bh*1024 + n0)*64;
    const float* rhg = relH + (bh*1024 + n0)*32;
    const float* rwg = relW + (bh*1024 + n0)*32;
    for (int i = 0; i < 2; i++){
      int offs = (wv*2 + i) * 512;
      gl2lds16(qg + offs + lane*8, Qt + offs + lane*8);
      int offf = (wv*2 + i) * 256;
      gl2lds16(rhg + offf + lane*4, rH + offf + lane*4);
      gl2lds16(rwg + offf + lane*4, rW + offf + lane*4);
    }
  }

  f32x4 O[4] = {};
  float mrow[4], lrow[4];
  for (int r = 0; r < 4; r++){ mrow[r] = -1e30f; lrow[r] = 0.f; }

  const short* kg = kb  + bh*1024*64;
  const short* vg = vtb + bh*64*1024;

  for (int step = 0; step < 16; step++){
    {
      const short* kt = kg + step*64*64;
      for (int i = 0; i < 2; i++){
        int offs = (wv*2 + i) * 512;
        gl2lds16(kt + offs + lane*8, Kt + offs + lane*8);
        int r0 = (wv*2 + i) * 8;
        int dd = r0 + (lane >> 3);
        gl2lds16(vg + dd*1024 + step*64 + (lane&7)*8, Vt + r0*64 + lane*8);
      }
    }
    __syncthreads();

    bf16x8 a0 = *(const bf16x8*)(Qt + (wv*16 + mi)*64 + quad*8);
    bf16x8 a1 = *(const bf16x8*)(Qt + (wv*16 + mi)*64 + 32 + quad*8);

    f32x4 S[4];
    for (int nt = 0; nt < 4; nt++){
      bf16x8 b0 = *(const bf16x8*)(Kt + (nt*16 + mi)*64 + quad*8);
      bf16x8 b1 = *(const bf16x8*)(Kt + (nt*16 + mi)*64 + 32 + quad*8);
      f32x4 c = {};
      c = mfma16(a0, b0, c);
      c = mfma16(a1, b1, c);
      S[nt] = c;
    }

    // bias: m = step*64 + nt*16 + mi  ->  kh = 2*step + (nt>>1), kw = (nt&1)*16 + mi
    float rh[2][4], rw2[2][4];
    for (int r = 0; r < 4; r++){
      int row = wv*16 + quad*4 + r;
      rh[0][r]  = rH[row*32 + 2*step];
      rh[1][r]  = rH[row*32 + 2*step + 1];
      rw2[0][r] = rW[row*32 + mi];
      rw2[1][r] = rW[row*32 + 16 + mi];
    }
    for (int nt = 0; nt < 4; nt++)
      for (int r = 0; r < 4; r++)
        S[nt][r] = S[nt][r]*0.125f + rh[nt>>1][r] + rw2[nt&1][r];

    float mx[4], al[4];
    for (int r = 0; r < 4; r++){
      float v = fmaxf(fmaxf(S[0][r], S[1][r]), fmaxf(S[2][r], S[3][r]));
      v = fmaxf(v, __shfl_xor(v, 1, 64));
      v = fmaxf(v, __shfl_xor(v, 2, 64));
      v = fmaxf(v, __shfl_xor(v, 4, 64));
      v = fmaxf(v, __shfl_xor(v, 8, 64));
      mx[r] = v;
    }
    for (int r = 0; r < 4; r++){
      float mnew = fmaxf(mrow[r], mx[r]);
      al[r] = __expf(mrow[r] - mnew);
      mrow[r] = mnew;
      float s = 0.f;
      for (int nt = 0; nt < 4; nt++){
        float p = __expf(S[nt][r] - mnew);
        S[nt][r] = p;
        s += p;
      }
      s += __shfl_xor(s, 1, 64);
      s += __shfl_xor(s, 2, 64);
      s += __shfl_xor(s, 4, 64);
      s += __shfl_xor(s, 8, 64);
      lrow[r] = lrow[r]*al[r] + s;
    }
    for (int t = 0; t < 4; t++)
      for (int r = 0; r < 4; r++)
        O[t][r] *= al[r];

    // P -> LDS (wave-private rows: no barrier needed, DS is in-order per wave)
    for (int nt = 0; nt < 4; nt++)
      for (int r = 0; r < 4; r++)
        Pt[(wv*16 + quad*4 + r)*64 + nt*16 + mi] = (short)f2bf(S[nt][r]);

    bf16x8 p0 = *(const bf16x8*)(Pt + (wv*16 + mi)*64 + quad*8);
    bf16x8 p1 = *(const bf16x8*)(Pt + (wv*16 + mi)*64 + 32 + quad*8);
    for (int t = 0; t < 4; t++){
      bf16x8 v0 = *(const bf16x8*)(Vt + (t*16 + mi)*64 + quad*8);
      bf16x8 v1 = *(const bf16x8*)(Vt + (t*16 + mi)*64 + 32 + quad*8);
      O[t] = mfma16(p0, v0, O[t]);
      O[t] = mfma16(p1, v1, O[t]);
    }
    __syncthreads();   // all waves done with Kt/Vt before next stage
  }

  int b_ = bh / 12, head = bh % 12;
  for (int t = 0; t < 4; t++)
    for (int r = 0; r < 4; r++){
      int n = n0 + wv*16 + quad*4 + r;
      float ov = O[t][r] / lrow[r];
      ao[(b_*1024 + n)*768 + head*64 + t*16 + mi] = (short)f2bf(ov);
    }
}

// ---------------------------------------------------------------- out proj
__global__ __launch_bounds__(256) void proj_kernel(const short* __restrict__ ao,
                                                   const short* __restrict__ woT,
                                                   const float* __restrict__ bias,
                                                   float* __restrict__ out){
  __shared__ __align__(16) short As[128*32];
  __shared__ __align__(16) short Bs[128*32];
  const int tid = threadIdx.x, lane = tid & 63, wv = tid >> 6;
  const int quad = lane >> 4, mi = lane & 15;
  const int m0 = blockIdx.x * 128, n0 = blockIdx.y * 128;
  const int wrow = wv >> 1, wcol = wv & 1;
  f32x4 acc[4][4] = {};
  for (int k0 = 0; k0 < 768; k0 += 32){
    __syncthreads();
    for (int i = 0; i < 2; i++){
      int rbase = 32*wv + 16*i;
      int row = rbase + (lane >> 2);
      gl2lds16(ao  + (m0+row)*768 + k0 + (lane&3)*8, As + rbase*32 + lane*8);
      gl2lds16(woT + (n0+row)*768 + k0 + (lane&3)*8, Bs + rbase*32 + lane*8);
    }
    __syncthreads();
    bf16x8 a[4], b[4];
    for (int mt = 0; mt < 4; mt++) a[mt] = *(const bf16x8*)(As + (wrow*64 + mt*16 + mi)*32 + quad*8);
    for (int nt = 0; nt < 4; nt++) b[nt] = *(const bf16x8*)(Bs + (wcol*64 + nt*16 + mi)*32 + quad*8);
    for (int mt = 0; mt < 4; mt++)
      for (int nt = 0; nt < 4; nt++)
        acc[mt][nt] = mfma16(a[mt], b[nt], acc[mt][nt]);
  }
  for (int nt = 0; nt < 4; nt++){
    int j = n0 + wcol*64 + nt*16 + mi;
    float bj = bias[j];
    for (int mt = 0; mt < 4; mt++)
      for (int r = 0; r < 4; r++){
        int m = m0 + wrow*64 + mt*16 + quad*4 + r;
        out[m*768 + j] = acc[mt][nt][r] + bj;
      }
  }
}

// ---------------------------------------------------------------- launch
extern "C" void kernel_launch(void* const* d_in, const int* in_sizes, int n_in,
                              void* d_out, int out_size, void* d_ws, size_t ws_size,
                              hipStream_t stream){
  const float* x     = (const float*)d_in[0];
  const float* w_qkv = (const float*)d_in[1];
  const float* w_out = (const float*)d_in[2];
  const float* b_out = (const float*)d_in[3];
  const float* rph   = (const float*)d_in[4];
  const float* rpw   = (const float*)d_in[5];
  float* out = (float*)d_out;
  char* ws = (char*)d_ws;
  short* xb   = (short*)(ws + 0);          // 4096x768 bf16    (6291456 B)
  short* wqT  = (short*)(ws + 6291456);    // 2304x768 bf16    (3538944 B)
  short* woT  = (short*)(ws + 9830400);    // 768x768 bf16     (1179648 B)
  short* qb   = (short*)(ws + 11010048);   // 48x1024x64 bf16  (6291456 B)
  short* kb   = (short*)(ws + 17301504);   // 48x1024x64 bf16  (6291456 B)
  short* vtb  = (short*)(ws + 23592960);   // 48x64x1024 bf16  (6291456 B)
  float* relH = (float*)(ws + 29884416);   // 48x32x32x32 f32  (6291456 B)
  float* relW = (float*)(ws + 36175872);   // 48x32x32x32 f32  (6291456 B)
  short* ao   = (short*)(ws + 42467328);   // 4096x768 bf16    (6291456 B)

  cast_x_kernel<<<1536, 256, 0, stream>>>(x, xb);
  transpose_cast_kernel<<<dim3(72, 24), 256, 0, stream>>>(w_qkv, wqT, 768, 2304);
  transpose_cast_kernel<<<dim3(24, 24), 256, 0, stream>>>(w_out, woT, 768, 768);
  qkv_gemm_kernel<<<dim3(32, 18), 256, 0, stream>>>(xb, wqT, qb, kb, vtb);
  rel_kernel<<<6144, 64, 0, stream>>>(qb, rph, rpw, relH, relW);
  flash_kernel<<<dim3(16, 48), 256, 0, stream>>>(qb, kb, vtb, relH, relW, ao);
  proj_kernel<<<dim3(32, 6), 256, 0, stream>>>(ao, woT, b_out, out);
}

// Round 2
// 196.777 us; speedup vs baseline: 1.1060x; 1.1060x over previous
//
#include <hip/hip_runtime.h>
#include <cstdint>

#define DEV __device__ __forceinline__

typedef __bf16  bf16x8 __attribute__((ext_vector_type(8)));
typedef short   s16x8  __attribute__((ext_vector_type(8)));
typedef float   f32x4  __attribute__((ext_vector_type(4)));

// fp32 -> bf16 round-to-nearest-even
DEV unsigned short f2bf(float f){
  union { float f; unsigned u; } v; v.f = f;
  unsigned r = v.u + 0x7fffu + ((v.u >> 16) & 1u);
  return (unsigned short)(r >> 16);
}

// async global->LDS, 16B per lane; LDS dest must be uniform_base + lane*16
DEV void gl2lds16(const void* g, void* l){
  __builtin_amdgcn_global_load_lds((__attribute__((address_space(1))) void*)(void*)(g),
                                   (__attribute__((address_space(3))) void*)(l), 16, 0, 0);
}

DEV f32x4 mfma16(bf16x8 a, bf16x8 b, f32x4 c){
  return __builtin_amdgcn_mfma_f32_16x16x32_bf16(a, b, c, 0, 0, 0);
}

// ---------------------------------------------------------------- prep
// blocks 0..1535: cast x (fp32->bf16). block 1536: cast rel tables.
__global__ __launch_bounds__(256) void cast_x_kernel(const float* __restrict__ in,
                                                     short* __restrict__ out,
                                                     const float* __restrict__ rph,
                                                     const float* __restrict__ rpw,
                                                     short* __restrict__ rphb,
                                                     short* __restrict__ rpwb){
  if (blockIdx.x < 1536){
    int i = blockIdx.x * 256 + threadIdx.x;
    const float4* in4 = (const float4*)in;
    float4 f0 = in4[i*2], f1 = in4[i*2+1];
    s16x8 o;
    o[0]=(short)f2bf(f0.x); o[1]=(short)f2bf(f0.y); o[2]=(short)f2bf(f0.z); o[3]=(short)f2bf(f0.w);
    o[4]=(short)f2bf(f1.x); o[5]=(short)f2bf(f1.y); o[6]=(short)f2bf(f1.z); o[7]=(short)f2bf(f1.w);
    *(s16x8*)(out + i*8) = o;
  } else {
    int t = threadIdx.x;
    for (int j = 0; j < 32; j++){
      int idx = t*32 + j;
      if (idx < 4032){
        rphb[idx] = (short)f2bf(rph[idx]);
        rpwb[idx] = (short)f2bf(rpw[idx]);
      }
    }
  }
}

// out[C][R] (bf16) = in[R][C] (fp32)
__global__ __launch_bounds__(256) void transpose_cast_kernel(const float* __restrict__ in,
                                                             short* __restrict__ out,
                                                             int R, int C){
  __shared__ float t[32][33];
  int tx = threadIdx.x & 31, ty = threadIdx.x >> 5;
  int c0 = blockIdx.x * 32, r0 = blockIdx.y * 32;
  for (int i = 0; i < 4; i++)
    t[ty + i*8][tx] = in[(r0 + ty + i*8)*C + c0 + tx];
  __syncthreads();
  for (int i = 0; i < 4; i++)
    out[(c0 + ty + i*8)*R + r0 + tx] = (short)f2bf(t[tx][ty + i*8]);
}

// ---------------------------------------------------------------- QKV GEMM (BK=64, XOR-swizzled LDS)
// C[m,j] = sum_k xb[m,k]*wqT[j,k];  M=4096 (b*1024+n), Ncols=2304, K=768
// epilogue: q,k,v all stored (bh, n, d) coalesced; v transposed later.
__global__ __launch_bounds__(256) void qkv_gemm_kernel(const short* __restrict__ xb,
                                                       const short* __restrict__ wqT,
                                                       short* __restrict__ qb,
                                                       short* __restrict__ kb,
                                                       short* __restrict__ vb){
  __shared__ __align__(16) short As[128*64];
  __shared__ __align__(16) short Bs[128*64];
  const int tid = threadIdx.x, lane = tid & 63, wv = tid >> 6;
  const int quad = lane >> 4, mi = lane & 15;
  const int m0 = blockIdx.x * 128, n0 = blockIdx.y * 128;
  const int wrow = wv >> 1, wcol = wv & 1;
  const int srow = lane >> 3, scs = lane & 7;
  const int sc = scs ^ (srow & 7);               // swizzled source chunk for staging
  f32x4 acc[4][4] = {};
  for (int k0 = 0; k0 < 768; k0 += 64){
    __syncthreads();
    for (int i = 0; i < 4; i++){
      int rbase = i*32 + wv*8;
      int row = rbase + srow;
      gl2lds16(xb  + (m0+row)*768 + k0 + sc*8, As + rbase*64 + lane*8);
      gl2lds16(wqT + (n0+row)*768 + k0 + sc*8, Bs + rbase*64 + lane*8);
    }
    __syncthreads();
    bf16x8 a[2][4], b[2][4];
    for (int kk = 0; kk < 2; kk++){
      int ccs = ((quad + kk*4) ^ (mi & 7)) * 8;  // row&7 == mi&7 for rows X*16+mi
      for (int mt = 0; mt < 4; mt++) a[kk][mt] = *(const bf16x8*)(As + (wrow*64 + mt*16 + mi)*64 + ccs);
      for (int nt = 0; nt < 4; nt++) b[kk][nt] = *(const bf16x8*)(Bs + (wcol*64 + nt*16 + mi)*64 + ccs);
    }
    for (int kk = 0; kk < 2; kk++)
      for (int mt = 0; mt < 4; mt++)
        for (int nt = 0; nt < 4; nt++)
          acc[mt][nt] = mfma16(a[kk][mt], b[kk][nt], acc[mt][nt]);
  }
  for (int nt = 0; nt < 4; nt++){
    int j = n0 + wcol*64 + nt*16 + mi;            // output col 0..2303
    int which = j / 768, rem = j % 768;
    int head = rem >> 6, d = rem & 63;
    short* dst = (which == 0) ? qb : (which == 1) ? kb : vb;
    for (int mt = 0; mt < 4; mt++)
      for (int r = 0; r < 4; r++){
        int m = m0 + wrow*64 + mt*16 + quad*4 + r;
        int bh = (m >> 10)*12 + head;
        dst[((bh << 10) + (m & 1023))*64 + d] = (short)f2bf(acc[mt][nt][r]);
      }
  }
}

// ---------------------------------------------------------------- v transpose: vb(bh,n,d) -> vtb(bh,d,n)
__global__ __launch_bounds__(256) void vtrans_kernel(const short* __restrict__ vb,
                                                     short* __restrict__ vtb){
  __shared__ __align__(16) short T[64*64];       // swizzled [key][d]
  int t = threadIdx.x;
  int bh = blockIdx.x >> 4, t0 = (blockIdx.x & 15) * 64;
  const short* src = vb + (bh*1024 + t0)*64;
  for (int p = 0; p < 2; p++){
    int row = p*32 + (t >> 3);
    int c = (t & 7) ^ (row & 7);
    gl2lds16(src + row*64 + c*8, T + p*2048 + t*8);
  }
  __syncthreads();
  int d = t >> 2, k4 = t & 3;
  short vals[16];
  for (int j = 0; j < 16; j++){
    int k = k4 + j*4;
    int cs = (d >> 3) ^ (k & 7);
    vals[j] = T[k*64 + cs*8 + (d & 7)];
  }
  short* dst = vtb + (bh*64 + d)*1024 + t0;
  for (int j = 0; j < 16; j++)
    dst[k4 + j*4] = vals[j];
}

// ---------------------------------------------------------------- rel bias (bf16 tables, 4-wave blocks)
__global__ __launch_bounds__(256) void rel_kernel(const short* __restrict__ qb,
                                                  const short* __restrict__ rphb,
                                                  const short* __restrict__ rpwb,
                                                  float* __restrict__ relH,
                                                  float* __restrict__ relW){
  int wv = threadIdx.x >> 6, lane = threadIdx.x & 63;
  int bid = blockIdx.x*4 + wv;
  int quad = lane >> 4, mi = lane & 15;
  f32x4 acc[2] = {};
  if (bid < 3072){
    int bh = bid >> 6, rest = bid & 63, h = rest >> 1, half = rest & 1;
    const short* qr = qb + (bh*1024 + h*32 + half*16 + mi)*64;
    bf16x8 a0 = *(const bf16x8*)(qr + quad*8);
    bf16x8 a1 = *(const bf16x8*)(qr + 32 + quad*8);
    for (int nt = 0; nt < 2; nt++){
      int kh = nt*16 + mi;
      const short* rr = rphb + (h - kh + 31)*64;
      bf16x8 b0 = *(const bf16x8*)(rr + quad*8);
      bf16x8 b1 = *(const bf16x8*)(rr + 32 + quad*8);
      acc[nt] = mfma16(a0, b0, acc[nt]);
      acc[nt] = mfma16(a1, b1, acc[nt]);
    }
    for (int nt = 0; nt < 2; nt++)
      for (int r = 0; r < 4; r++){
        int w = half*16 + quad*4 + r;
        relH[((bh*32 + h)*32 + w)*32 + nt*16 + mi] = acc[nt][r];
      }
  } else {
    int bid2 = bid - 3072, w = bid2 / 96, rt = bid2 % 96;
    int rg = rt*16 + mi, bh = rg >> 5, h = rg & 31;
    const short* qr = qb + (bh*1024 + h*32 + w)*64;
    bf16x8 a0 = *(const bf16x8*)(qr + quad*8);
    bf16x8 a1 = *(const bf16x8*)(qr + 32 + quad*8);
    for (int nt = 0; nt < 2; nt++){
      int kw = nt*16 + mi;
      const short* rr = rpwb + (w - kw + 31)*64;
      bf16x8 b0 = *(const bf16x8*)(rr + quad*8);
      bf16x8 b1 = *(const bf16x8*)(rr + 32 + quad*8);
      acc[nt] = mfma16(a0, b0, acc[nt]);
      acc[nt] = mfma16(a1, b1, acc[nt]);
    }
    for (int nt = 0; nt < 2; nt++)
      for (int r = 0; r < 4; r++){
        int rowg = rt*16 + quad*4 + r;                    // = bh*32+h of the output row
        relW[(rowg*32 + w)*32 + nt*16 + mi] = acc[nt][r];
      }
  }
}

// ---------------------------------------------------------------- flash attention (XOR-swizzled LDS)
// grid (16 q-tiles, 48 bh); 64x64 tiles; online softmax; ao[b,n,head*64+d] bf16
__global__ __launch_bounds__(256) void flash_kernel(const short* __restrict__ qb,
                                                    const short* __restrict__ kb,
                                                    const short* __restrict__ vtb,
                                                    const float* __restrict__ relH,
                                                    const float* __restrict__ relW,
                                                    short* __restrict__ ao){
  __shared__ __align__(16) short Qt[64*64];
  __shared__ __align__(16) short Kt[64*64];
  __shared__ __align__(16) short Vt[64*64];   // [d][key], swizzled
  __shared__ __align__(16) short Pt[64*64];   // [qrow][key], swizzled
  __shared__ __align__(16) float rH[64*32];
  __shared__ __align__(16) float rW[64*32];
  const int tid = threadIdx.x, lane = tid & 63, wv = tid >> 6;
  const int quad = lane >> 4, mi = lane & 15;
  const int bh = blockIdx.y, n0 = blockIdx.x * 64;
  const int sw0 = (quad ^ (mi & 7)) * 8;
  const int sw1 = ((quad + 4) ^ (mi & 7)) * 8;

  {
    const short* qg  = qb   + (bh*1024 + n0)*64;
    const float* rhg = relH + (bh*1024 + n0)*32;
    const float* rwg = relW + (bh*1024 + n0)*32;
    for (int i = 0; i < 2; i++){
      int slab = wv*2 + i;                       // 0..7
      int rbase = slab*8;
      int row = rbase + (lane >> 3);
      int c = (lane & 7) ^ (row & 7);
      gl2lds16(qg + row*64 + c*8, Qt + rbase*64 + lane*8);
      int offf = slab*256;
      gl2lds16(rhg + offf + lane*4, rH + offf + lane*4);
      gl2lds16(rwg + offf + lane*4, rW + offf + lane*4);
    }
  }

  f32x4 O[4] = {};
  float mrow[4], lrow[4];
  for (int r = 0; r < 4; r++){ mrow[r] = -1e30f; lrow[r] = 0.f; }

  const short* kg = kb  + bh*1024*64;
  const short* vg = vtb + bh*64*1024;

  __syncthreads();   // Qt/rH/rW ready (also covers first K/V staging ordering)
  // step-invariant rW values
  float rwA[4], rwB[4];
  for (int r = 0; r < 4; r++){
    int row = wv*16 + quad*4 + r;
    rwA[r] = rW[row*32 + mi];
    rwB[r] = rW[row*32 + 16 + mi];
  }

  for (int step = 0; step < 16; step++){
    {
      const short* kt = kg + step*64*64;
      for (int i = 0; i < 2; i++){
        int slab = wv*2 + i, rbase = slab*8;
        int row = rbase + (lane >> 3);
        int c = (lane & 7) ^ (row & 7);
        gl2lds16(kt + row*64 + c*8, Kt + rbase*64 + lane*8);
        gl2lds16(vg + row*1024 + step*64 + c*8, Vt + rbase*64 + lane*8);
      }
    }
    __syncthreads();

    bf16x8 a0 = *(const bf16x8*)(Qt + (wv*16 + mi)*64 + sw0);
    bf16x8 a1 = *(const bf16x8*)(Qt + (wv*16 + mi)*64 + sw1);

    f32x4 S[4];
    for (int nt = 0; nt < 4; nt++){
      bf16x8 b0 = *(const bf16x8*)(Kt + (nt*16 + mi)*64 + sw0);
      bf16x8 b1 = *(const bf16x8*)(Kt + (nt*16 + mi)*64 + sw1);
      f32x4 c = {};
      c = mfma16(a0, b0, c);
      c = mfma16(a1, b1, c);
      S[nt] = c;
    }

    // bias: key m = step*64 + nt*16 + mi  ->  kh = 2*step + (nt>>1), kw = (nt&1)*16 + mi
    float rh0[4], rh1[4];
    for (int r = 0; r < 4; r++){
      int row = wv*16 + quad*4 + r;
      float2 rr = *(const float2*)(rH + row*32 + 2*step);
      rh0[r] = rr.x; rh1[r] = rr.y;
    }
    for (int nt = 0; nt < 4; nt++)
      for (int r = 0; r < 4; r++)
        S[nt][r] = S[nt][r]*0.125f + ((nt>>1) ? rh1[r] : rh0[r]) + ((nt&1) ? rwB[r] : rwA[r]);

    float al[4];
    for (int r = 0; r < 4; r++){
      float v = fmaxf(fmaxf(S[0][r], S[1][r]), fmaxf(S[2][r], S[3][r]));
      v = fmaxf(v, __shfl_xor(v, 1, 64));
      v = fmaxf(v, __shfl_xor(v, 2, 64));
      v = fmaxf(v, __shfl_xor(v, 4, 64));
      v = fmaxf(v, __shfl_xor(v, 8, 64));
      float mnew = fmaxf(mrow[r], v);
      al[r] = __expf(mrow[r] - mnew);
      mrow[r] = mnew;
      float s = 0.f;
      for (int nt = 0; nt < 4; nt++){
        float p = __expf(S[nt][r] - mnew);
        S[nt][r] = p;
        s += p;
      }
      s += __shfl_xor(s, 1, 64);
      s += __shfl_xor(s, 2, 64);
      s += __shfl_xor(s, 4, 64);
      s += __shfl_xor(s, 8, 64);
      lrow[r] = lrow[r]*al[r] + s;
    }
    for (int t = 0; t < 4; t++)
      for (int r = 0; r < 4; r++)
        O[t][r] *= al[r];

    // P -> LDS (wave-private rows, swizzled; DS in-order per wave so no barrier)
    for (int nt = 0; nt < 4; nt++)
      for (int r = 0; r < 4; r++){
        int row = wv*16 + quad*4 + r;
        int col = nt*16 + mi;
        int cs = (col >> 3) ^ (row & 7);
        Pt[row*64 + cs*8 + (col & 7)] = (short)f2bf(S[nt][r]);
      }

    bf16x8 p0 = *(const bf16x8*)(Pt + (wv*16 + mi)*64 + sw0);
    bf16x8 p1 = *(const bf16x8*)(Pt + (wv*16 + mi)*64 + sw1);
    for (int t = 0; t < 4; t++){
      bf16x8 v0 = *(const bf16x8*)(Vt + (t*16 + mi)*64 + sw0);
      bf16x8 v1 = *(const bf16x8*)(Vt + (t*16 + mi)*64 + sw1);
      O[t] = mfma16(p0, v0, O[t]);
      O[t] = mfma16(p1, v1, O[t]);
    }
    __syncthreads();   // all waves done with Kt/Vt before next stage
  }

  int b_ = bh / 12, head = bh % 12;
  for (int t = 0; t < 4; t++)
    for (int r = 0; r < 4; r++){
      int n = n0 + wv*16 + quad*4 + r;
      float ov = O[t][r] / lrow[r];
      ao[(b_*1024 + n)*768 + head*64 + t*16 + mi] = (short)f2bf(ov);
    }
}

// ---------------------------------------------------------------- out proj (BK=64, swizzled)
__global__ __launch_bounds__(256) void proj_kernel(const short* __restrict__ ao,
                                                   const short* __restrict__ woT,
                                                   const float* __restrict__ bias,
                                                   float* __restrict__ out){
  __shared__ __align__(16) short As[128*64];
  __shared__ __align__(16) short Bs[128*64];
  const int tid = threadIdx.x, lane = tid & 63, wv = tid >> 6;
  const int quad = lane >> 4, mi = lane & 15;
  const int m0 = blockIdx.x * 128, n0 = blockIdx.y * 128;
  const int wrow = wv >> 1, wcol = wv & 1;
  const int srow = lane >> 3, scs = lane & 7;
  const int sc = scs ^ (srow & 7);
  f32x4 acc[4][4] = {};
  for (int k0 = 0; k0 < 768; k0 += 64){
    __syncthreads();
    for (int i = 0; i < 4; i++){
      int rbase = i*32 + wv*8;
      int row = rbase + srow;
      gl2lds16(ao  + (m0+row)*768 + k0 + sc*8, As + rbase*64 + lane*8);
      gl2lds16(woT + (n0+row)*768 + k0 + sc*8, Bs + rbase*64 + lane*8);
    }
    __syncthreads();
    bf16x8 a[2][4], b[2][4];
    for (int kk = 0; kk < 2; kk++){
      int ccs = ((quad + kk*4) ^ (mi & 7)) * 8;
      for (int mt = 0; mt < 4; mt++) a[kk][mt] = *(const bf16x8*)(As + (wrow*64 + mt*16 + mi)*64 + ccs);
      for (int nt = 0; nt < 4; nt++) b[kk][nt] = *(const bf16x8*)(Bs + (wcol*64 + nt*16 + mi)*64 + ccs);
    }
    for (int kk = 0; kk < 2; kk++)
      for (int mt = 0; mt < 4; mt++)
        for (int nt = 0; nt < 4; nt++)
          acc[mt][nt] = mfma16(a[kk][mt], b[kk][nt], acc[mt][nt]);
  }
  for (int nt = 0; nt < 4; nt++){
    int j = n0 + wcol*64 + nt*16 + mi;
    float bj = bias[j];
    for (int mt = 0; mt < 4; mt++)
      for (int r = 0; r < 4; r++){
        int m = m0 + wrow*64 + mt*16 + quad*4 + r;
        out[m*768 + j] = acc[mt][nt][r] + bj;
      }
  }
}

// ---------------------------------------------------------------- launch
extern "C" void kernel_launch(void* const* d_in, const int* in_sizes, int n_in,
                              void* d_out, int out_size, void* d_ws, size_t ws_size,
                              hipStream_t stream){
  const float* x     = (const float*)d_in[0];
  const float* w_qkv = (const float*)d_in[1];
  const float* w_out = (const float*)d_in[2];
  const float* b_out = (const float*)d_in[3];
  const float* rph   = (const float*)d_in[4];
  const float* rpw   = (const float*)d_in[5];
  float* out = (float*)d_out;
  char* ws = (char*)d_ws;
  short* xb   = (short*)(ws + 0);          // 4096x768 bf16 (reused as ao after qkv)
  short* wqT  = (short*)(ws + 6291456);    // 2304x768 bf16
  short* woT  = (short*)(ws + 9830400);    // 768x768 bf16
  short* qb   = (short*)(ws + 11010048);   // 48x1024x64 bf16
  short* kb   = (short*)(ws + 17301504);   // 48x1024x64 bf16
  short* vb   = (short*)(ws + 23592960);   // 48x1024x64 bf16
  short* vtb  = (short*)(ws + 29884416);   // 48x64x1024 bf16
  float* relH = (float*)(ws + 36175872);   // 48x32x32x32 f32
  float* relW = (float*)(ws + 42467328);   // 48x32x32x32 f32
  short* rphb = (short*)(ws + 48758784);   // 63x64 bf16
  short* rpwb = (short*)(ws + 48775168);   // 63x64 bf16
  short* ao   = xb;                        // reuse (xb dead after qkv_gemm)

  cast_x_kernel<<<1537, 256, 0, stream>>>(x, xb, rph, rpw, rphb, rpwb);
  transpose_cast_kernel<<<dim3(72, 24), 256, 0, stream>>>(w_qkv, wqT, 768, 2304);
  transpose_cast_kernel<<<dim3(24, 24), 256, 0, stream>>>(w_out, woT, 768, 768);
  qkv_gemm_kernel<<<dim3(32, 18), 256, 0, stream>>>(xb, wqT, qb, kb, vb);
  vtrans_kernel<<<768, 256, 0, stream>>>(vb, vtb);
  rel_kernel<<<1536, 256, 0, stream>>>(qb, rphb, rpwb, relH, relW);
  flash_kernel<<<dim3(16, 48), 256, 0, stream>>>(qb, kb, vtb, relH, relW, ao);
  proj_kernel<<<dim3(32, 6), 256, 0, stream>>>(ao, woT, b_out, out);
}

// Round 3
// 173.883 us; speedup vs baseline: 1.2516x; 1.1317x over previous
//
#include <hip/hip_runtime.h>
#include <cstdint>

#define DEV __device__ __forceinline__

typedef __bf16  bf16x8 __attribute__((ext_vector_type(8)));
typedef short   s16x8  __attribute__((ext_vector_type(8)));
typedef float   f32x4  __attribute__((ext_vector_type(4)));

// fp32 -> bf16 round-to-nearest-even
DEV unsigned short f2bf(float f){
  union { float f; unsigned u; } v; v.f = f;
  unsigned r = v.u + 0x7fffu + ((v.u >> 16) & 1u);
  return (unsigned short)(r >> 16);
}

// pack two positive f32 -> 2 bf16 (round-half-up) in one dword: lo in low16
DEV unsigned pk2(float lo, float hi){
  unsigned a = __builtin_bit_cast(unsigned, lo) + 0x8000u;
  unsigned b = __builtin_bit_cast(unsigned, hi) + 0x8000u;
  return __builtin_amdgcn_perm(b, a, 0x07060302);  // {hi16(b),hi16(a)}
}

// async global->LDS, 16B per lane; LDS dest must be uniform_base + lane*16
DEV void gl2lds16(const void* g, void* l){
  __builtin_amdgcn_global_load_lds((__attribute__((address_space(1))) void*)(void*)(g),
                                   (__attribute__((address_space(3))) void*)(l), 16, 0, 0);
}

DEV f32x4 mfma16(bf16x8 a, bf16x8 b, f32x4 c){
  return __builtin_amdgcn_mfma_f32_16x16x32_bf16(a, b, c, 0, 0, 0);
}

// ---------------------------------------------------------------- prep (merged)
// blocks 0..1535: cast x; 1536: rel tables (*8); 1537..3264: transpose w_qkv;
// 3265..3840: transpose w_out
__global__ __launch_bounds__(256) void prep_kernel(const float* __restrict__ x,
                                                   short* __restrict__ xb,
                                                   const float* __restrict__ rph,
                                                   const float* __restrict__ rpw,
                                                   short* __restrict__ rphb,
                                                   short* __restrict__ rpwb,
                                                   const float* __restrict__ w_qkv,
                                                   short* __restrict__ wqT,
                                                   const float* __restrict__ w_out,
                                                   short* __restrict__ woT){
  __shared__ float tb[32][33];
  int b = blockIdx.x;
  if (b < 1536){
    int i = b * 256 + threadIdx.x;
    const float4* in4 = (const float4*)x;
    float4 f0 = in4[i*2], f1 = in4[i*2+1];
    s16x8 o;
    o[0]=(short)f2bf(f0.x); o[1]=(short)f2bf(f0.y); o[2]=(short)f2bf(f0.z); o[3]=(short)f2bf(f0.w);
    o[4]=(short)f2bf(f1.x); o[5]=(short)f2bf(f1.y); o[6]=(short)f2bf(f1.z); o[7]=(short)f2bf(f1.w);
    *(s16x8*)(xb + i*8) = o;
  } else if (b == 1536){
    int t = threadIdx.x;
    for (int j = 0; j < 16; j++){
      int idx = t*16 + j;
      if (idx < 4032){
        rphb[idx] = (short)f2bf(rph[idx] * 8.f);   // *8 compensates q pre-scaled by 1/8
        rpwb[idx] = (short)f2bf(rpw[idx] * 8.f);
      }
    }
  } else {
    const float* in; short* out; int R, C, bx, by;
    if (b < 3265){ int t = b - 1537; in = w_qkv; out = wqT; R = 768; C = 2304; bx = t % 72; by = t / 72; }
    else         { int t = b - 3265; in = w_out; out = woT; R = 768; C = 768;  bx = t % 24; by = t / 24; }
    int tx = threadIdx.x & 31, ty = threadIdx.x >> 5;
    int c0 = bx * 32, r0 = by * 32;
    for (int i = 0; i < 4; i++)
      tb[ty + i*8][tx] = in[(r0 + ty + i*8)*C + c0 + tx];
    __syncthreads();
    for (int i = 0; i < 4; i++)
      out[(c0 + ty + i*8)*R + r0 + tx] = (short)f2bf(tb[tx][ty + i*8]);
  }
}

// ---------------------------------------------------------------- QKV GEMM (BK=64, XOR-swizzled LDS)
// q stored PRE-SCALED by 0.125; q,k,v all (bh, n, d) coalesced; v transposed later.
__global__ __launch_bounds__(256) void qkv_gemm_kernel(const short* __restrict__ xb,
                                                       const short* __restrict__ wqT,
                                                       short* __restrict__ qb,
                                                       short* __restrict__ kb,
                                                       short* __restrict__ vb){
  __shared__ __align__(16) short As[128*64];
  __shared__ __align__(16) short Bs[128*64];
  const int tid = threadIdx.x, lane = tid & 63, wv = tid >> 6;
  const int quad = lane >> 4, mi = lane & 15;
  const int m0 = blockIdx.x * 128, n0 = blockIdx.y * 128;
  const int wrow = wv >> 1, wcol = wv & 1;
  const int srow = lane >> 3, scs = lane & 7;
  const int sc = scs ^ (srow & 7);
  f32x4 acc[4][4] = {};
  for (int k0 = 0; k0 < 768; k0 += 64){
    __syncthreads();
    for (int i = 0; i < 4; i++){
      int rbase = i*32 + wv*8;
      int row = rbase + srow;
      gl2lds16(xb  + (m0+row)*768 + k0 + sc*8, As + rbase*64 + lane*8);
      gl2lds16(wqT + (n0+row)*768 + k0 + sc*8, Bs + rbase*64 + lane*8);
    }
    __syncthreads();
    bf16x8 a[2][4], b[2][4];
    for (int kk = 0; kk < 2; kk++){
      int ccs = ((quad + kk*4) ^ (mi & 7)) * 8;
      for (int mt = 0; mt < 4; mt++) a[kk][mt] = *(const bf16x8*)(As + (wrow*64 + mt*16 + mi)*64 + ccs);
      for (int nt = 0; nt < 4; nt++) b[kk][nt] = *(const bf16x8*)(Bs + (wcol*64 + nt*16 + mi)*64 + ccs);
    }
    for (int kk = 0; kk < 2; kk++)
      for (int mt = 0; mt < 4; mt++)
        for (int nt = 0; nt < 4; nt++)
          acc[mt][nt] = mfma16(a[kk][mt], b[kk][nt], acc[mt][nt]);
  }
  const int which = n0 / 768;                    // uniform per block
  const float qs = (which == 0) ? 0.125f : 1.0f;
  for (int nt = 0; nt < 4; nt++){
    int j = n0 + wcol*64 + nt*16 + mi;
    int rem = j % 768;
    int head = rem >> 6, d = rem & 63;
    short* dst = (which == 0) ? qb : (which == 1) ? kb : vb;
    for (int mt = 0; mt < 4; mt++)
      for (int r = 0; r < 4; r++){
        int m = m0 + wrow*64 + mt*16 + quad*4 + r;
        int bh = (m >> 10)*12 + head;
        dst[((bh << 10) + (m & 1023))*64 + d] = (short)f2bf(acc[mt][nt][r] * qs);
      }
  }
}

// ---------------------------------------------------------------- rel bias + v transpose (merged)
// blocks 0..1535: rel (4 waves, bid=blk*4+wv over 6144 jobs); 1536..2303: vtrans
__global__ __launch_bounds__(256) void relvt_kernel(const short* __restrict__ qb,
                                                    const short* __restrict__ rphb,
                                                    const short* __restrict__ rpwb,
                                                    float* __restrict__ relH,
                                                    float* __restrict__ relW,
                                                    const short* __restrict__ vb,
                                                    short* __restrict__ vtb){
  __shared__ __align__(16) short T[64*64];
  if (blockIdx.x < 1536){
    int wv = threadIdx.x >> 6, lane = threadIdx.x & 63;
    int bid = blockIdx.x*4 + wv;
    int quad = lane >> 4, mi = lane & 15;
    f32x4 acc[2] = {};
    if (bid < 3072){
      int bh = bid >> 6, rest = bid & 63, h = rest >> 1, half = rest & 1;
      const short* qr = qb + (bh*1024 + h*32 + half*16 + mi)*64;
      bf16x8 a0 = *(const bf16x8*)(qr + quad*8);
      bf16x8 a1 = *(const bf16x8*)(qr + 32 + quad*8);
      for (int nt = 0; nt < 2; nt++){
        int kh = nt*16 + mi;
        const short* rr = rphb + (h - kh + 31)*64;
        bf16x8 b0 = *(const bf16x8*)(rr + quad*8);
        bf16x8 b1 = *(const bf16x8*)(rr + 32 + quad*8);
        acc[nt] = mfma16(a0, b0, acc[nt]);
        acc[nt] = mfma16(a1, b1, acc[nt]);
      }
      for (int nt = 0; nt < 2; nt++)
        for (int r = 0; r < 4; r++){
          int w = half*16 + quad*4 + r;
          relH[((bh*32 + h)*32 + w)*32 + nt*16 + mi] = acc[nt][r];
        }
    } else {
      int bid2 = bid - 3072, w = bid2 / 96, rt = bid2 % 96;
      int rg = rt*16 + mi, bh = rg >> 5, h = rg & 31;
      const short* qr = qb + (bh*1024 + h*32 + w)*64;
      bf16x8 a0 = *(const bf16x8*)(qr + quad*8);
      bf16x8 a1 = *(const bf16x8*)(qr + 32 + quad*8);
      for (int nt = 0; nt < 2; nt++){
        int kw = nt*16 + mi;
        const short* rr = rpwb + (w - kw + 31)*64;
        bf16x8 b0 = *(const bf16x8*)(rr + quad*8);
        bf16x8 b1 = *(const bf16x8*)(rr + 32 + quad*8);
        acc[nt] = mfma16(a0, b0, acc[nt]);
        acc[nt] = mfma16(a1, b1, acc[nt]);
      }
      for (int nt = 0; nt < 2; nt++)
        for (int r = 0; r < 4; r++){
          int rowg = rt*16 + quad*4 + r;
          relW[(rowg*32 + w)*32 + nt*16 + mi] = acc[nt][r];
        }
    }
  } else {
    int blk = blockIdx.x - 1536;
    int t = threadIdx.x;
    int bh = blk >> 4, t0 = (blk & 15) * 64;
    const short* src = vb + (bh*1024 + t0)*64;
    for (int p = 0; p < 2; p++){
      int row = p*32 + (t >> 3);
      int c = (t & 7) ^ (row & 7);
      gl2lds16(src + row*64 + c*8, T + p*2048 + t*8);
    }
    __syncthreads();
    int d = t >> 2, k4 = t & 3;
    short vals[16];
    for (int j = 0; j < 16; j++){
      int k = k4 + j*4;
      int cs = (d >> 3) ^ (k & 7);
      vals[j] = T[k*64 + cs*8 + (d & 7)];
    }
    short* dst = vtb + (bh*64 + d)*1024 + t0;
    for (int j = 0; j < 16; j++)
      dst[k4 + j*4] = vals[j];
  }
}

// ---------------------------------------------------------------- flash attention (S^T layout)
// grid (16 q-tiles, 48 bh); 64x64 tiles; each lane owns ONE q-row (qrow=wv*16+mi)
__global__ __launch_bounds__(256, 3) void flash_kernel(const short* __restrict__ qb,
                                                       const short* __restrict__ kb,
                                                       const short* __restrict__ vtb,
                                                       const float* __restrict__ relH,
                                                       const float* __restrict__ relW,
                                                       short* __restrict__ ao){
  __shared__ __align__(16) short Qt[64*64];
  __shared__ __align__(16) short Kt[64*64];
  __shared__ __align__(16) short Vt[64*64];   // [d][key], swizzled
  __shared__ __align__(16) short Pt[64*64];   // [qrow][key], swizzled
  __shared__ __align__(16) float rHs[64*32];
  __shared__ __align__(16) float rWs[64*32];
  const int tid = threadIdx.x, lane = tid & 63, wv = tid >> 6;
  const int quad = lane >> 4, mi = lane & 15;
  const int bh = blockIdx.y, n0 = blockIdx.x * 64;
  const int sw0 = (quad ^ (mi & 7)) * 8;
  const int sw1 = ((quad + 4) ^ (mi & 7)) * 8;
  const int qrow = wv*16 + mi;

  {
    const short* qg  = qb   + (bh*1024 + n0)*64;
    const float* rhg = relH + (bh*1024 + n0)*32;
    const float* rwg = relW + (bh*1024 + n0)*32;
    for (int i = 0; i < 2; i++){
      int slab = wv*2 + i, rbase = slab*8;
      int row = rbase + (lane >> 3);
      int c = (lane & 7) ^ (row & 7);
      gl2lds16(qg + row*64 + c*8, Qt + rbase*64 + lane*8);
      int offf = slab*256;
      gl2lds16(rhg + offf + lane*4, rHs + offf + lane*4);
      gl2lds16(rwg + offf + lane*4, rWs + offf + lane*4);
    }
  }

  f32x4 O[4] = {};
  float m_ = -1e30f, l_ = 0.f;
  float rh[32], rw[2][4];
  bf16x8 qf0, qf1;
  const short* kg = kb  + bh*1024*64;
  const short* vg = vtb + bh*64*1024;

#pragma unroll
  for (int step = 0; step < 16; step++){
    {
      const short* kt = kg + step*64*64;
      for (int i = 0; i < 2; i++){
        int slab = wv*2 + i, rbase = slab*8;
        int row = rbase + (lane >> 3);
        int c = (lane & 7) ^ (row & 7);
        gl2lds16(kt + row*64 + c*8, Kt + rbase*64 + lane*8);
        gl2lds16(vg + row*1024 + step*64 + c*8, Vt + rbase*64 + lane*8);
      }
    }
    __syncthreads();

    if (step == 0){
      qf0 = *(const bf16x8*)(Qt + qrow*64 + sw0);
      qf1 = *(const bf16x8*)(Qt + qrow*64 + sw1);
      for (int c = 0; c < 8; c++){
        float4 v4 = *(const float4*)(rHs + qrow*32 + c*4);
        rh[c*4+0]=v4.x; rh[c*4+1]=v4.y; rh[c*4+2]=v4.z; rh[c*4+3]=v4.w;
      }
      for (int s = 0; s < 2; s++)
        for (int r = 0; r < 4; r++)
          rw[s][r] = rWs[qrow*32 + s*16 + quad*4 + r];
    }

    // S^T: A = K-frag (rows=keys), B = Q-frag (cols=qrows)
    f32x4 S[4];
    for (int nt = 0; nt < 4; nt++){
      bf16x8 kf0 = *(const bf16x8*)(Kt + (nt*16 + mi)*64 + sw0);
      bf16x8 kf1 = *(const bf16x8*)(Kt + (nt*16 + mi)*64 + sw1);
      f32x4 c = {};
      c = mfma16(kf0, qf0, c);
      c = mfma16(kf1, qf1, c);
      S[nt] = c;   // lane: qrow fixed, key = nt*16 + quad*4 + r
    }
    // bias: key o = nt*16+quad*4+r -> kh = 2*step + (nt>>1), kw = (nt&1)*16+quad*4+r
    float kh0 = rh[2*step], kh1 = rh[2*step + 1];
    for (int nt = 0; nt < 4; nt++){
      float kh = (nt & 2) ? kh1 : kh0;
      for (int r = 0; r < 4; r++)
        S[nt][r] += kh + rw[nt & 1][r];
    }
    // row max over lane's 16 + quads (lanes mi, mi+16, mi+32, mi+48)
    float mx = S[0][0];
    for (int nt = 0; nt < 4; nt++)
      for (int r = 0; r < 4; r++)
        mx = fmaxf(mx, S[nt][r]);
    mx = fmaxf(mx, __shfl_xor(mx, 16, 64));
    mx = fmaxf(mx, __shfl_xor(mx, 32, 64));
    float mnew = fmaxf(m_, mx);
    float al = __expf(m_ - mnew);
    m_ = mnew;
    float s = 0.f;
    for (int nt = 0; nt < 4; nt++)
      for (int r = 0; r < 4; r++){
        float p = __expf(S[nt][r] - mnew);
        S[nt][r] = p;
        s += p;
      }
    s += __shfl_xor(s, 16, 64);
    s += __shfl_xor(s, 32, 64);
    l_ = l_*al + s;
    // rescale O (O rows = wv*16+quad*4+r; alpha lives at lane idx quad*4+r)
    float alr[4];
    for (int r = 0; r < 4; r++) alr[r] = __shfl(al, quad*4 + r, 64);
    for (int t = 0; t < 4; t++)
      for (int r = 0; r < 4; r++)
        O[t][r] *= alr[r];
    // P -> LDS: row qrow, cols nt*16+quad*4+{0..3}: 4x ds_write_b64, swizzled
    for (int nt = 0; nt < 4; nt++){
      unsigned u0 = pk2(S[nt][0], S[nt][1]);
      unsigned u1 = pk2(S[nt][2], S[nt][3]);
      int chunk = (2*nt + (quad >> 1)) ^ (mi & 7);
      uint2 uu; uu.x = u0; uu.y = u1;
      *(uint2*)(Pt + qrow*64 + chunk*8 + (quad & 1)*4) = uu;
    }
    // PV (wave-private Pt rows: no barrier needed)
    bf16x8 p0 = *(const bf16x8*)(Pt + qrow*64 + sw0);
    bf16x8 p1 = *(const bf16x8*)(Pt + qrow*64 + sw1);
    for (int t = 0; t < 4; t++){
      bf16x8 v0 = *(const bf16x8*)(Vt + (t*16 + mi)*64 + sw0);
      bf16x8 v1 = *(const bf16x8*)(Vt + (t*16 + mi)*64 + sw1);
      O[t] = mfma16(p0, v0, O[t]);
      O[t] = mfma16(p1, v1, O[t]);
    }
    __syncthreads();
  }

  float inv[4];
  for (int r = 0; r < 4; r++) inv[r] = 1.f / __shfl(l_, quad*4 + r, 64);
  int b_ = bh / 12, head = bh % 12;
  for (int t = 0; t < 4; t++)
    for (int r = 0; r < 4; r++){
      int n = n0 + wv*16 + quad*4 + r;
      ao[(b_*1024 + n)*768 + head*64 + t*16 + mi] = (short)f2bf(O[t][r] * inv[r]);
    }
}

// ---------------------------------------------------------------- out proj (128x64 tiles, 384 blocks)
__global__ __launch_bounds__(256) void proj_kernel(const short* __restrict__ ao,
                                                   const short* __restrict__ woT,
                                                   const float* __restrict__ bias,
                                                   float* __restrict__ out){
  __shared__ __align__(16) short As[128*64];
  __shared__ __align__(16) short Bs[64*64];
  const int tid = threadIdx.x, lane = tid & 63, wv = tid >> 6;
  const int quad = lane >> 4, mi = lane & 15;
  const int m0 = blockIdx.x * 128, n0 = blockIdx.y * 64;
  const int srow = lane >> 3, sc = (lane & 7) ^ (srow & 7);
  f32x4 acc[2][4] = {};
  for (int k0 = 0; k0 < 768; k0 += 64){
    __syncthreads();
    for (int i = 0; i < 4; i++){
      int rbase = i*32 + wv*8, row = rbase + srow;
      gl2lds16(ao + (m0+row)*768 + k0 + sc*8, As + rbase*64 + lane*8);
    }
    for (int i = 0; i < 2; i++){
      int rbase = i*32 + wv*8, row = rbase + srow;
      gl2lds16(woT + (n0+row)*768 + k0 + sc*8, Bs + rbase*64 + lane*8);
    }
    __syncthreads();
    for (int kk = 0; kk < 2; kk++){
      int ccs = ((quad + kk*4) ^ (mi & 7)) * 8;
      bf16x8 a[2], b[4];
      for (int mt = 0; mt < 2; mt++) a[mt] = *(const bf16x8*)(As + (wv*32 + mt*16 + mi)*64 + ccs);
      for (int nt = 0; nt < 4; nt++) b[nt] = *(const bf16x8*)(Bs + (nt*16 + mi)*64 + ccs);
      for (int mt = 0; mt < 2; mt++)
        for (int nt = 0; nt < 4; nt++)
          acc[mt][nt] = mfma16(a[mt], b[nt], acc[mt][nt]);
    }
  }
  for (int nt = 0; nt < 4; nt++){
    int j = n0 + nt*16 + mi;
    float bj = bias[j];
    for (int mt = 0; mt < 2; mt++)
      for (int r = 0; r < 4; r++){
        int m = m0 + wv*32 + mt*16 + quad*4 + r;
        out[m*768 + j] = acc[mt][nt][r] + bj;
      }
  }
}

// ---------------------------------------------------------------- launch
extern "C" void kernel_launch(void* const* d_in, const int* in_sizes, int n_in,
                              void* d_out, int out_size, void* d_ws, size_t ws_size,
                              hipStream_t stream){
  const float* x     = (const float*)d_in[0];
  const float* w_qkv = (const float*)d_in[1];
  const float* w_out = (const float*)d_in[2];
  const float* b_out = (const float*)d_in[3];
  const float* rph   = (const float*)d_in[4];
  const float* rpw   = (const float*)d_in[5];
  float* out = (float*)d_out;
  char* ws = (char*)d_ws;
  short* xb   = (short*)(ws + 0);          // 4096x768 bf16 (reused as ao after qkv)
  short* wqT  = (short*)(ws + 6291456);    // 2304x768 bf16
  short* woT  = (short*)(ws + 9830400);    // 768x768 bf16
  short* qb   = (short*)(ws + 11010048);   // 48x1024x64 bf16 (pre-scaled 1/8)
  short* kb   = (short*)(ws + 17301504);   // 48x1024x64 bf16
  short* vb   = (short*)(ws + 23592960);   // 48x1024x64 bf16
  short* vtb  = (short*)(ws + 29884416);   // 48x64x1024 bf16
  float* relH = (float*)(ws + 36175872);   // 48x32x32x32 f32
  float* relW = (float*)(ws + 42467328);   // 48x32x32x32 f32
  short* rphb = (short*)(ws + 48758784);   // 63x64 bf16 (*8)
  short* rpwb = (short*)(ws + 48775168);   // 63x64 bf16 (*8)
  short* ao   = xb;                        // reuse

  prep_kernel<<<3841, 256, 0, stream>>>(x, xb, rph, rpw, rphb, rpwb, w_qkv, wqT, w_out, woT);
  qkv_gemm_kernel<<<dim3(32, 18), 256, 0, stream>>>(xb, wqT, qb, kb, vb);
  relvt_kernel<<<2304, 256, 0, stream>>>(qb, rphb, rpwb, relH, relW, vb, vtb);
  flash_kernel<<<dim3(16, 48), 256, 0, stream>>>(qb, kb, vtb, relH, relW, ao);
  proj_kernel<<<dim3(32, 12), 256, 0, stream>>>(ao, woT, b_out, out);
}